// Round 6
// baseline (474.166 us; speedup 1.0000x reference)
//
#include <hip/hip_runtime.h>
#include <hip/hip_bf16.h>

#define BS    8
#define NQ    16384
#define CDIM  128
#define NH    8
#define NPROJ 224            // 128 value + 64 off + 32 attn logits
#define M_TOTAL (BS*NQ)      // 131072 rows

typedef __bf16 bf16_t;
typedef __bf16 bf16x8 __attribute__((ext_vector_type(8)));
typedef __bf16 bf16x4 __attribute__((ext_vector_type(4)));
typedef float  f32x4  __attribute__((ext_vector_type(4)));
typedef unsigned int u32;

__device__ __forceinline__ bf16x8 cvt_bf16x8(const float* p) {
    float4 a = *(const float4*)p;
    float4 b = *(const float4*)(p + 4);
    bf16x8 r;
    r[0] = (bf16_t)a.x; r[1] = (bf16_t)a.y; r[2] = (bf16_t)a.z; r[3] = (bf16_t)a.w;
    r[4] = (bf16_t)b.x; r[5] = (bf16_t)b.y; r[6] = (bf16_t)b.z; r[7] = (bf16_t)b.w;
    return r;
}
__device__ __forceinline__ float bflo(u32 d) { return __uint_as_float(d << 16); }
__device__ __forceinline__ float bfhi(u32 d) { return __uint_as_float(d & 0xffff0000u); }

// ---------------------------------------------------------------------------
// Kernel 0: one-shot weight transpose to bf16.
// WT rows: [0,128) WvT | [128,192) WoffT | [192,224) WattnT | [224,352) WoutT
// WT[n][k] = W[k][n], row-major [352][128] bf16.
// ---------------------------------------------------------------------------
__global__ void wtrans_kernel(const float* __restrict__ Wv, const float* __restrict__ Woff,
                              const float* __restrict__ Wattn, const float* __restrict__ Wout,
                              bf16_t* __restrict__ WT)
{
    const int i = blockIdx.x * 256 + threadIdx.x;   // grid covers 352*128 exactly
    const int n = i >> 7, k = i & 127;
    float v;
    if (n < 128)      v = Wv[k*128 + n];
    else if (n < 192) v = Woff[k*64 + (n-128)];
    else if (n < 224) v = Wattn[k*32 + (n-192)];
    else              v = Wout[k*128 + (n-224)];
    WT[i] = (bf16_t)v;
}

// ---------------------------------------------------------------------------
// Kernel 1: fused projections  P = query @ [Wv | Woff | Wattn] + bias
// 256 rows/block (grid 512 = exactly 2 blocks/CU, whole grid resident in one
// pass; Bt staged once per 256 rows). Operand-swapped MFMA; A = W^T tile in
// LDS (R3: de-staging thrashes L2 - keep). Two independent row-groups per
// wave for 2x MFMA/load ILP.
// Outputs: value HEAD-MAJOR [b][h][q][16]; off HEAD-MAJOR [b][h][q][8];
//          attn HEAD-MAJOR [b][h][q][4].
// ---------------------------------------------------------------------------
__global__ __launch_bounds__(512, 4)
void proj_kernel(const float* __restrict__ query, const bf16_t* __restrict__ WT,
                 const float* __restrict__ bv, const float* __restrict__ boff,
                 const float* __restrict__ battn,
                 bf16_t* __restrict__ value, bf16_t* __restrict__ offb,
                 bf16_t* __restrict__ attnb)
{
    __shared__ bf16_t Bt[NPROJ][136];   // Bt[n][k] = W[k][n], padded
    __shared__ float  bias[NPROJ];
    const int t = threadIdx.x;

    // vectorized stage: 224 rows x 16 chunks of 8 bf16
    for (int i = t; i < NPROJ*16; i += 512) {
        const int n = i >> 4, c = i & 15;
        *(bf16x8*)&Bt[n][c*8] = *(const bf16x8*)(WT + n*128 + c*8);
    }
    if (t < 128)      bias[t] = bv[t];
    else if (t < 192) bias[t] = boff[t-128];
    else if (t < 224) bias[t] = battn[t-192];
    __syncthreads();

    const int lane = t & 63;
    const int wave = t >> 6;           // 0..7
    const int ln   = lane & 15;
    const int q4   = lane >> 4;
    const int lk   = q4 * 8;

    // two row-groups per wave: rows row0 and row0+128
    const int row0 = blockIdx.x * 256 + wave * 16 + ln;

    bf16x8 qf[2][4];
    #pragma unroll
    for (int g = 0; g < 2; ++g) {
        const float* ap = query + (row0 + g*128) * CDIM + lk;
        #pragma unroll
        for (int kc = 0; kc < 4; ++kc)
            qf[g][kc] = cvt_bf16x8(ap + kc*32);
    }

    #pragma unroll 1
    for (int cb = 0; cb < 14; ++cb) {
        const int n0 = cb * 16;
        bf16x8 wf[4];
        const bf16_t* bp = &Bt[n0 + ln][lk];   // A-operand: channel n0+ln
        #pragma unroll
        for (int kc = 0; kc < 4; ++kc)
            wf[kc] = *(const bf16x8*)(bp + kc*32);

        f32x4 acc0 = {0.f, 0.f, 0.f, 0.f};
        f32x4 acc1 = {0.f, 0.f, 0.f, 0.f};
        #pragma unroll
        for (int kc = 0; kc < 4; ++kc) {
            acc0 = __builtin_amdgcn_mfma_f32_16x16x32_bf16(wf[kc], qf[0][kc], acc0, 0, 0, 0);
            acc1 = __builtin_amdgcn_mfma_f32_16x16x32_bf16(wf[kc], qf[1][kc], acc1, 0, 0, 0);
        }

        const int c0 = n0 + q4*4;              // first of 4 consecutive channels
        const f32x4 bi = *(const f32x4*)&bias[c0];

        #pragma unroll
        for (int g = 0; g < 2; ++g) {
            const f32x4 acc = g ? acc1 : acc0;
            const int row = row0 + g*128;
            const int b   = row >> 14;
            const int q   = row & (NQ - 1);
            bf16x4 s;
            #pragma unroll
            for (int r = 0; r < 4; ++r) s[r] = (bf16_t)(acc[r] + bi[r]);

            if (cb < 8) {
                const int h = c0 >> 4;          // cb == head
                *(bf16x4*)(value + (((size_t)(b*8 + h) << 14) + q)*16 + (c0 & 15)) = s;
            } else if (cb < 12) {
                const int h    = (c0 - 128) >> 3;
                const int part = (c0 - 128) & 7;        // 0 or 4
                *(bf16x4*)(offb + (((size_t)(b*8 + h) << 14) + q)*8 + part) = s;
            } else {
                const int h = (c0 - 192) >> 2;          // full logit quad
                *(bf16x4*)(attnb + (((size_t)(b*8 + h) << 14) + q)*4) = s;
            }
        }
    }
}

// ---------------------------------------------------------------------------
// Kernel 2 (fused sample + out-proj):
// Phase 1: 64 query rows/block; ONE thread per (row,h) unit (all 16 channels):
//          softmax/offset/address math computed once per unit (was 2x);
//          each tap loads the full 32B pixel as two adjacent dwordx4.
//          Wave = 1 head x 64 consecutive rows -> contiguous tap addresses;
//          off/attn reads fully coalesced (head-major buffers).
// Phase 2: operand-swapped MFMA vs Wout^T staged in LDS (R3: de-staging
//          thrashes L2); epilogue +bout+2*query, packed float4 stores.
// ---------------------------------------------------------------------------
__global__ __launch_bounds__(512, 6)
void sample_out_kernel(const bf16_t* __restrict__ value, const bf16_t* __restrict__ offb,
                       const bf16_t* __restrict__ attnb, const bf16_t* __restrict__ WTo,
                       const float* __restrict__ bout, const float* __restrict__ query,
                       float* __restrict__ out)
{
    __shared__ bf16_t Wt[128][136];     // Wout^T
    __shared__ float  bias[128];
    __shared__ bf16_t Srow[64][136];    // sampled rows tile (pad 8)
    const int t = threadIdx.x;

    for (int i = t; i < 128*16; i += 512) {
        const int n = i >> 4, c = i & 15;
        *(bf16x8*)&Wt[n][c*8] = *(const bf16x8*)(WTo + n*128 + c*8);
    }
    if (t < 128) bias[t] = bout[t];

    const int row_base = blockIdx.x * 64;
    {
        const int h  = t >> 6;         // wave = head
        const int lr = t & 63;         // lane = row within tile
        const int bq = row_base + lr;
        const int q  = bq & (NQ - 1);
        const int b  = bq >> 14;
        const size_t plane = (size_t)(b*8 + h) << 14;   // (b,h) pixel plane

        // softmax over 4 points (logits bf16; |l| < ~2, no max-sub needed)
        union { bf16x4 v; u32 d[2]; } at;
        at.v = *(const bf16x4*)(attnb + (plane + q)*4);
        float e0 = __expf(bflo(at.d[0])), e1 = __expf(bfhi(at.d[0]));
        float e2 = __expf(bflo(at.d[1])), e3 = __expf(bfhi(at.d[1]));
        float rs = 1.0f / (e0 + e1 + e2 + e3);
        const float aw[4] = {e0*rs, e1*rs, e2*rs, e3*rs};

        union { bf16x8 v; u32 d[4]; } of;
        of.v = *(const bf16x8*)(offb + (plane + q)*8);

        const float bx = (float)(q & 127) * (128.0f/127.0f) - 0.5f;
        const float by = (float)(q >> 7)  * (128.0f/127.0f) - 0.5f;

        const bf16_t* vbase = value + plane*16;

        float a[16];
        #pragma unroll
        for (int r = 0; r < 16; ++r) a[r] = 0.f;

        #pragma unroll
        for (int p = 0; p < 4; ++p) {
            float x = bx + bflo(of.d[p]);
            float y = by + bfhi(of.d[p]);
            float xf = floorf(x), yf = floorf(y);
            int   x0 = (int)xf,  y0 = (int)yf;
            float wx1 = x - xf, wy1 = y - yf;
            float wxe0 = (((unsigned)x0       < 128u) ? (1.0f - wx1) : 0.f);
            float wxe1 = (((unsigned)(x0 + 1) < 128u) ? wx1          : 0.f);
            float wye0 = (((unsigned)y0       < 128u) ? (1.0f - wy1) : 0.f) * aw[p];
            float wye1 = (((unsigned)(y0 + 1) < 128u) ? wy1          : 0.f) * aw[p];
            int xc0 = min(max(x0, 0), 127),      xc1 = min(max(x0 + 1, 0), 127);
            int rb0 = min(max(y0, 0), 127) << 7, rb1 = min(max(y0 + 1, 0), 127) << 7;

            const int   idx[4] = {rb0 + xc0, rb0 + xc1, rb1 + xc0, rb1 + xc1};
            const float wt [4] = {wxe0*wye0, wxe1*wye0, wxe0*wye1, wxe1*wye1};
            #pragma unroll
            for (int tp = 0; tp < 4; ++tp) {
                const bf16_t* pp = vbase + ((size_t)idx[tp] << 4);
                const uint4 dA = *(const uint4*)pp;
                const uint4 dB = *(const uint4*)(pp + 8);
                const float w = wt[tp];
                a[0]  += w * bflo(dA.x); a[1]  += w * bfhi(dA.x);
                a[2]  += w * bflo(dA.y); a[3]  += w * bfhi(dA.y);
                a[4]  += w * bflo(dA.z); a[5]  += w * bfhi(dA.z);
                a[6]  += w * bflo(dA.w); a[7]  += w * bfhi(dA.w);
                a[8]  += w * bflo(dB.x); a[9]  += w * bfhi(dB.x);
                a[10] += w * bflo(dB.y); a[11] += w * bfhi(dB.y);
                a[12] += w * bflo(dB.z); a[13] += w * bfhi(dB.z);
                a[14] += w * bflo(dB.w); a[15] += w * bfhi(dB.w);
            }
        }
        bf16x8 s0, s1;
        #pragma unroll
        for (int r = 0; r < 8; ++r) { s0[r] = (bf16_t)a[r]; s1[r] = (bf16_t)a[8+r]; }
        *(bf16x8*)(&Srow[lr][h*16])     = s0;
        *(bf16x8*)(&Srow[lr][h*16 + 8]) = s1;
    }
    __syncthreads();

    // Phase 2: 8 waves x 4 jobs: row-tile rt = wave>>1, col-blocks (wave&1)*4..+3
    const int lane = t & 63;
    const int wave = t >> 6;
    const int ln   = lane & 15;
    const int q4   = lane >> 4;
    const int lk   = q4 * 8;
    const int rt   = wave >> 1;
    const int cb0  = (wave & 1) * 4;

    bf16x8 sf[4];
    const bf16_t* sp = &Srow[rt*16 + ln][lk];   // B-operand: sampled row
    #pragma unroll
    for (int kc = 0; kc < 4; ++kc)
        sf[kc] = *(const bf16x8*)(sp + kc*32);

    const int grow = row_base + rt*16 + ln;     // global row this lane stores

    #pragma unroll
    for (int c = 0; c < 4; ++c) {
        const int n0 = (cb0 + c) * 16;
        bf16x8 wf[4];
        const bf16_t* bp = &Wt[n0 + ln][lk];    // A-operand: out channel n0+ln
        #pragma unroll
        for (int kc = 0; kc < 4; ++kc)
            wf[kc] = *(const bf16x8*)(bp + kc*32);

        f32x4 acc = {0.f, 0.f, 0.f, 0.f};
        #pragma unroll
        for (int kc = 0; kc < 4; ++kc)
            acc = __builtin_amdgcn_mfma_f32_16x16x32_bf16(wf[kc], sf[kc], acc, 0, 0, 0);

        const int c0 = n0 + q4*4;
        const f32x4 bi = *(const f32x4*)&bias[c0];
        const float4 qv = *(const float4*)(query + grow*CDIM + c0);
        float4 o;
        o.x = acc[0] + bi[0] + 2.0f*qv.x;
        o.y = acc[1] + bi[1] + 2.0f*qv.y;
        o.z = acc[2] + bi[2] + 2.0f*qv.z;
        o.w = acc[3] + bi[3] + 2.0f*qv.w;
        *(float4*)(out + grow*CDIM + c0) = o;
    }
}

// ---------------------------------------------------------------------------
extern "C" void kernel_launch(void* const* d_in, const int* in_sizes, int n_in,
                              void* d_out, int out_size, void* d_ws, size_t ws_size,
                              hipStream_t stream)
{
    const float* query = (const float*)d_in[0];
    const float* Wv    = (const float*)d_in[1];
    const float* bv    = (const float*)d_in[2];
    const float* Woff  = (const float*)d_in[3];
    const float* boff  = (const float*)d_in[4];
    const float* Wattn = (const float*)d_in[5];
    const float* battn = (const float*)d_in[6];
    const float* Wout  = (const float*)d_in[7];
    const float* bout  = (const float*)d_in[8];
    float* out = (float*)d_out;

    // ws: value bf16 head-major (33.5MB) | off bf16 head-major (16.8MB)
    //     | attnl bf16 head-major (8.4MB) | WT bf16 [352][128] (90KB)
    bf16_t* value = (bf16_t*)d_ws;
    bf16_t* offb  = (bf16_t*)((char*)d_ws + (size_t)M_TOTAL*CDIM*2);
    bf16_t* attnb = (bf16_t*)((char*)d_ws + (size_t)M_TOTAL*CDIM*2 + (size_t)M_TOTAL*64*2);
    bf16_t* WT    = (bf16_t*)((char*)d_ws + (size_t)M_TOTAL*CDIM*2 + (size_t)M_TOTAL*64*2
                                          + (size_t)M_TOTAL*32*2);
    bf16_t* WTo   = WT + 224*128;

    wtrans_kernel<<<(352*128)/256, 256, 0, stream>>>(Wv, Woff, Wattn, Wout, WT);
    proj_kernel<<<M_TOTAL/256, 512, 0, stream>>>(query, WT, bv, boff, battn,
                                                 value, offb, attnb);
    sample_out_kernel<<<M_TOTAL/64, 512, 0, stream>>>(value, offb, attnb,
                                                      WTo, bout, query, out);
}

// Round 7
// 304.940 us; speedup vs baseline: 1.5549x; 1.5549x over previous
//
#include <hip/hip_runtime.h>
#include <hip/hip_bf16.h>

#define BS    8
#define NQ    16384
#define CDIM  128
#define NH    8
#define NPROJ 224            // 128 value + 64 off + 32 attn logits
#define M_TOTAL (BS*NQ)      // 131072 rows

typedef __bf16 bf16_t;
typedef __bf16 bf16x8 __attribute__((ext_vector_type(8)));
typedef __bf16 bf16x4 __attribute__((ext_vector_type(4)));
typedef float  f32x4  __attribute__((ext_vector_type(4)));
typedef unsigned int u32;

__device__ __forceinline__ bf16x8 cvt_bf16x8(const float* p) {
    float4 a = *(const float4*)p;
    float4 b = *(const float4*)(p + 4);
    bf16x8 r;
    r[0] = (bf16_t)a.x; r[1] = (bf16_t)a.y; r[2] = (bf16_t)a.z; r[3] = (bf16_t)a.w;
    r[4] = (bf16_t)b.x; r[5] = (bf16_t)b.y; r[6] = (bf16_t)b.z; r[7] = (bf16_t)b.w;
    return r;
}
__device__ __forceinline__ float bflo(u32 d) { return __uint_as_float(d << 16); }
__device__ __forceinline__ float bfhi(u32 d) { return __uint_as_float(d & 0xffff0000u); }

// ---------------------------------------------------------------------------
// Kernel 0: one-shot weight transpose to bf16.
// WT rows: [0,128) WvT | [128,192) WoffT | [192,224) WattnT | [224,352) WoutT
// WT[n][k] = W[k][n], row-major [352][128] bf16.
// ---------------------------------------------------------------------------
__global__ void wtrans_kernel(const float* __restrict__ Wv, const float* __restrict__ Woff,
                              const float* __restrict__ Wattn, const float* __restrict__ Wout,
                              bf16_t* __restrict__ WT)
{
    const int i = blockIdx.x * 256 + threadIdx.x;   // grid covers 352*128 exactly
    const int n = i >> 7, k = i & 127;
    float v;
    if (n < 128)      v = Wv[k*128 + n];
    else if (n < 192) v = Woff[k*64 + (n-128)];
    else if (n < 224) v = Wattn[k*32 + (n-192)];
    else              v = Wout[k*128 + (n-224)];
    WT[i] = (bf16_t)v;
}

// ---------------------------------------------------------------------------
// Kernel 1: fused projections  P = query @ [Wv | Woff | Wattn] + bias
// 256 rows/block (grid 512 = exactly 2 blocks/CU, whole grid resident in one
// pass; Bt staged once per 256 rows). Operand-swapped MFMA; A = W^T tile in
// LDS (R3: de-staging thrashes L2 - keep). Two independent row-groups per
// wave for 2x MFMA/load ILP.
// Outputs: value HEAD-MAJOR [b][h][q][16]; off HEAD-MAJOR [b][h][q][8];
//          attn HEAD-MAJOR [b][h][q][4].
// ---------------------------------------------------------------------------
__global__ __launch_bounds__(512, 4)
void proj_kernel(const float* __restrict__ query, const bf16_t* __restrict__ WT,
                 const float* __restrict__ bv, const float* __restrict__ boff,
                 const float* __restrict__ battn,
                 bf16_t* __restrict__ value, bf16_t* __restrict__ offb,
                 bf16_t* __restrict__ attnb)
{
    __shared__ bf16_t Bt[NPROJ][136];   // Bt[n][k] = W[k][n], padded
    __shared__ float  bias[NPROJ];
    const int t = threadIdx.x;

    // vectorized stage: 224 rows x 16 chunks of 8 bf16
    for (int i = t; i < NPROJ*16; i += 512) {
        const int n = i >> 4, c = i & 15;
        *(bf16x8*)&Bt[n][c*8] = *(const bf16x8*)(WT + n*128 + c*8);
    }
    if (t < 128)      bias[t] = bv[t];
    else if (t < 192) bias[t] = boff[t-128];
    else if (t < 224) bias[t] = battn[t-192];
    __syncthreads();

    const int lane = t & 63;
    const int wave = t >> 6;           // 0..7
    const int ln   = lane & 15;
    const int q4   = lane >> 4;
    const int lk   = q4 * 8;

    // two row-groups per wave: rows row0 and row0+128
    const int row0 = blockIdx.x * 256 + wave * 16 + ln;

    bf16x8 qf[2][4];
    #pragma unroll
    for (int g = 0; g < 2; ++g) {
        const float* ap = query + (row0 + g*128) * CDIM + lk;
        #pragma unroll
        for (int kc = 0; kc < 4; ++kc)
            qf[g][kc] = cvt_bf16x8(ap + kc*32);
    }

    #pragma unroll 1
    for (int cb = 0; cb < 14; ++cb) {
        const int n0 = cb * 16;
        bf16x8 wf[4];
        const bf16_t* bp = &Bt[n0 + ln][lk];   // A-operand: channel n0+ln
        #pragma unroll
        for (int kc = 0; kc < 4; ++kc)
            wf[kc] = *(const bf16x8*)(bp + kc*32);

        f32x4 acc0 = {0.f, 0.f, 0.f, 0.f};
        f32x4 acc1 = {0.f, 0.f, 0.f, 0.f};
        #pragma unroll
        for (int kc = 0; kc < 4; ++kc) {
            acc0 = __builtin_amdgcn_mfma_f32_16x16x32_bf16(wf[kc], qf[0][kc], acc0, 0, 0, 0);
            acc1 = __builtin_amdgcn_mfma_f32_16x16x32_bf16(wf[kc], qf[1][kc], acc1, 0, 0, 0);
        }

        const int c0 = n0 + q4*4;              // first of 4 consecutive channels
        const f32x4 bi = *(const f32x4*)&bias[c0];

        #pragma unroll
        for (int g = 0; g < 2; ++g) {
            const f32x4 acc = g ? acc1 : acc0;
            const int row = row0 + g*128;
            const int b   = row >> 14;
            const int q   = row & (NQ - 1);
            bf16x4 s;
            #pragma unroll
            for (int r = 0; r < 4; ++r) s[r] = (bf16_t)(acc[r] + bi[r]);

            if (cb < 8) {
                const int h = c0 >> 4;          // cb == head
                *(bf16x4*)(value + (((size_t)(b*8 + h) << 14) + q)*16 + (c0 & 15)) = s;
            } else if (cb < 12) {
                const int h    = (c0 - 128) >> 3;
                const int part = (c0 - 128) & 7;        // 0 or 4
                *(bf16x4*)(offb + (((size_t)(b*8 + h) << 14) + q)*8 + part) = s;
            } else {
                const int h = (c0 - 192) >> 2;          // full logit quad
                *(bf16x4*)(attnb + (((size_t)(b*8 + h) << 14) + q)*4) = s;
            }
        }
    }
}

// ---------------------------------------------------------------------------
// Kernel 2 (fused sample + out-proj):
// Phase 1: 64 query rows/block; ONE thread per (row,h) unit (all 16 channels):
//          softmax/offset/address math computed once per unit;
//          each tap loads the full 32B pixel as two adjacent dwordx4.
//          Wave = 1 head x 64 consecutive rows -> contiguous tap addresses;
//          off/attn reads fully coalesced (head-major buffers).
//          launch_bounds (512,4): R6's (512,6) capped VGPR at 40 -> the a[16]
//          accumulators spilled to scratch (WRITE_SIZE 78->731 MB, 5.6x dur).
// Phase 2: operand-swapped MFMA vs Wout^T staged in LDS (R3: de-staging
//          thrashes L2); epilogue +bout+2*query, packed float4 stores.
// ---------------------------------------------------------------------------
__global__ __launch_bounds__(512, 4)
void sample_out_kernel(const bf16_t* __restrict__ value, const bf16_t* __restrict__ offb,
                       const bf16_t* __restrict__ attnb, const bf16_t* __restrict__ WTo,
                       const float* __restrict__ bout, const float* __restrict__ query,
                       float* __restrict__ out)
{
    __shared__ bf16_t Wt[128][136];     // Wout^T
    __shared__ float  bias[128];
    __shared__ bf16_t Srow[64][136];    // sampled rows tile (pad 8)
    const int t = threadIdx.x;

    for (int i = t; i < 128*16; i += 512) {
        const int n = i >> 4, c = i & 15;
        *(bf16x8*)&Wt[n][c*8] = *(const bf16x8*)(WTo + n*128 + c*8);
    }
    if (t < 128) bias[t] = bout[t];

    const int row_base = blockIdx.x * 64;
    {
        const int h  = t >> 6;         // wave = head
        const int lr = t & 63;         // lane = row within tile
        const int bq = row_base + lr;
        const int q  = bq & (NQ - 1);
        const int b  = bq >> 14;
        const size_t plane = (size_t)(b*8 + h) << 14;   // (b,h) pixel plane

        // softmax over 4 points (logits bf16; |l| < ~2, no max-sub needed)
        union { bf16x4 v; u32 d[2]; } at;
        at.v = *(const bf16x4*)(attnb + (plane + q)*4);
        float e0 = __expf(bflo(at.d[0])), e1 = __expf(bfhi(at.d[0]));
        float e2 = __expf(bflo(at.d[1])), e3 = __expf(bfhi(at.d[1]));
        float rs = 1.0f / (e0 + e1 + e2 + e3);
        const float aw[4] = {e0*rs, e1*rs, e2*rs, e3*rs};

        union { bf16x8 v; u32 d[4]; } of;
        of.v = *(const bf16x8*)(offb + (plane + q)*8);

        const float bx = (float)(q & 127) * (128.0f/127.0f) - 0.5f;
        const float by = (float)(q >> 7)  * (128.0f/127.0f) - 0.5f;

        const bf16_t* vbase = value + plane*16;

        float a[16];
        #pragma unroll
        for (int r = 0; r < 16; ++r) a[r] = 0.f;

        #pragma unroll
        for (int p = 0; p < 4; ++p) {
            float x = bx + bflo(of.d[p]);
            float y = by + bfhi(of.d[p]);
            float xf = floorf(x), yf = floorf(y);
            int   x0 = (int)xf,  y0 = (int)yf;
            float wx1 = x - xf, wy1 = y - yf;
            float wxe0 = (((unsigned)x0       < 128u) ? (1.0f - wx1) : 0.f);
            float wxe1 = (((unsigned)(x0 + 1) < 128u) ? wx1          : 0.f);
            float wye0 = (((unsigned)y0       < 128u) ? (1.0f - wy1) : 0.f) * aw[p];
            float wye1 = (((unsigned)(y0 + 1) < 128u) ? wy1          : 0.f) * aw[p];
            int xc0 = min(max(x0, 0), 127),      xc1 = min(max(x0 + 1, 0), 127);
            int rb0 = min(max(y0, 0), 127) << 7, rb1 = min(max(y0 + 1, 0), 127) << 7;

            const int   idx[4] = {rb0 + xc0, rb0 + xc1, rb1 + xc0, rb1 + xc1};
            const float wt [4] = {wxe0*wye0, wxe1*wye0, wxe0*wye1, wxe1*wye1};
            #pragma unroll
            for (int tp = 0; tp < 4; ++tp) {
                const bf16_t* pp = vbase + ((size_t)idx[tp] << 4);
                const uint4 dA = *(const uint4*)pp;
                const uint4 dB = *(const uint4*)(pp + 8);
                const float w = wt[tp];
                a[0]  += w * bflo(dA.x); a[1]  += w * bfhi(dA.x);
                a[2]  += w * bflo(dA.y); a[3]  += w * bfhi(dA.y);
                a[4]  += w * bflo(dA.z); a[5]  += w * bfhi(dA.z);
                a[6]  += w * bflo(dA.w); a[7]  += w * bfhi(dA.w);
                a[8]  += w * bflo(dB.x); a[9]  += w * bfhi(dB.x);
                a[10] += w * bflo(dB.y); a[11] += w * bfhi(dB.y);
                a[12] += w * bflo(dB.z); a[13] += w * bfhi(dB.z);
                a[14] += w * bflo(dB.w); a[15] += w * bfhi(dB.w);
            }
        }
        bf16x8 s0, s1;
        #pragma unroll
        for (int r = 0; r < 8; ++r) { s0[r] = (bf16_t)a[r]; s1[r] = (bf16_t)a[8+r]; }
        *(bf16x8*)(&Srow[lr][h*16])     = s0;
        *(bf16x8*)(&Srow[lr][h*16 + 8]) = s1;
    }
    __syncthreads();

    // Phase 2: 8 waves x 4 jobs: row-tile rt = wave>>1, col-blocks (wave&1)*4..+3
    const int lane = t & 63;
    const int wave = t >> 6;
    const int ln   = lane & 15;
    const int q4   = lane >> 4;
    const int lk   = q4 * 8;
    const int rt   = wave >> 1;
    const int cb0  = (wave & 1) * 4;

    bf16x8 sf[4];
    const bf16_t* sp = &Srow[rt*16 + ln][lk];   // B-operand: sampled row
    #pragma unroll
    for (int kc = 0; kc < 4; ++kc)
        sf[kc] = *(const bf16x8*)(sp + kc*32);

    const int grow = row_base + rt*16 + ln;     // global row this lane stores

    #pragma unroll
    for (int c = 0; c < 4; ++c) {
        const int n0 = (cb0 + c) * 16;
        bf16x8 wf[4];
        const bf16_t* bp = &Wt[n0 + ln][lk];    // A-operand: out channel n0+ln
        #pragma unroll
        for (int kc = 0; kc < 4; ++kc)
            wf[kc] = *(const bf16x8*)(bp + kc*32);

        f32x4 acc = {0.f, 0.f, 0.f, 0.f};
        #pragma unroll
        for (int kc = 0; kc < 4; ++kc)
            acc = __builtin_amdgcn_mfma_f32_16x16x32_bf16(wf[kc], sf[kc], acc, 0, 0, 0);

        const int c0 = n0 + q4*4;
        const f32x4 bi = *(const f32x4*)&bias[c0];
        const float4 qv = *(const float4*)(query + grow*CDIM + c0);
        float4 o;
        o.x = acc[0] + bi[0] + 2.0f*qv.x;
        o.y = acc[1] + bi[1] + 2.0f*qv.y;
        o.z = acc[2] + bi[2] + 2.0f*qv.z;
        o.w = acc[3] + bi[3] + 2.0f*qv.w;
        *(float4*)(out + grow*CDIM + c0) = o;
    }
}

// ---------------------------------------------------------------------------
extern "C" void kernel_launch(void* const* d_in, const int* in_sizes, int n_in,
                              void* d_out, int out_size, void* d_ws, size_t ws_size,
                              hipStream_t stream)
{
    const float* query = (const float*)d_in[0];
    const float* Wv    = (const float*)d_in[1];
    const float* bv    = (const float*)d_in[2];
    const float* Woff  = (const float*)d_in[3];
    const float* boff  = (const float*)d_in[4];
    const float* Wattn = (const float*)d_in[5];
    const float* battn = (const float*)d_in[6];
    const float* Wout  = (const float*)d_in[7];
    const float* bout  = (const float*)d_in[8];
    float* out = (float*)d_out;

    // ws: value bf16 head-major (33.5MB) | off bf16 head-major (16.8MB)
    //     | attnl bf16 head-major (8.4MB) | WT bf16 [352][128] (90KB)
    bf16_t* value = (bf16_t*)d_ws;
    bf16_t* offb  = (bf16_t*)((char*)d_ws + (size_t)M_TOTAL*CDIM*2);
    bf16_t* attnb = (bf16_t*)((char*)d_ws + (size_t)M_TOTAL*CDIM*2 + (size_t)M_TOTAL*64*2);
    bf16_t* WT    = (bf16_t*)((char*)d_ws + (size_t)M_TOTAL*CDIM*2 + (size_t)M_TOTAL*64*2
                                          + (size_t)M_TOTAL*32*2);
    bf16_t* WTo   = WT + 224*128;

    wtrans_kernel<<<(352*128)/256, 256, 0, stream>>>(Wv, Woff, Wattn, Wout, WT);
    proj_kernel<<<M_TOTAL/256, 512, 0, stream>>>(query, WT, bv, boff, battn,
                                                 value, offb, attnb);
    sample_out_kernel<<<M_TOTAL/64, 512, 0, stream>>>(value, offb, attnb,
                                                      WTo, bout, query, out);
}

// Round 8
// 183.220 us; speedup vs baseline: 2.5880x; 1.6643x over previous
//
#include <hip/hip_runtime.h>
#include <hip/hip_bf16.h>

#define BS    8
#define NQ    16384
#define CDIM  128
#define NH    8
#define NPROJ 224            // 128 value + 64 off + 32 attn logits
#define M_TOTAL (BS*NQ)      // 131072 rows

typedef __bf16 bf16_t;
typedef __bf16 bf16x8 __attribute__((ext_vector_type(8)));
typedef __bf16 bf16x4 __attribute__((ext_vector_type(4)));
typedef float  f32x4  __attribute__((ext_vector_type(4)));
typedef unsigned int u32;

__device__ __forceinline__ bf16x8 cvt_bf16x8(const float* p) {
    float4 a = *(const float4*)p;
    float4 b = *(const float4*)(p + 4);
    bf16x8 r;
    r[0] = (bf16_t)a.x; r[1] = (bf16_t)a.y; r[2] = (bf16_t)a.z; r[3] = (bf16_t)a.w;
    r[4] = (bf16_t)b.x; r[5] = (bf16_t)b.y; r[6] = (bf16_t)b.z; r[7] = (bf16_t)b.w;
    return r;
}
__device__ __forceinline__ float bflo(u32 d) { return __uint_as_float(d << 16); }
__device__ __forceinline__ float bfhi(u32 d) { return __uint_as_float(d & 0xffff0000u); }

// ---------------------------------------------------------------------------
// Kernel 0: one-shot weight transpose to bf16.
// WT rows: [0,128) WvT | [128,192) WoffT | [192,224) WattnT | [224,352) WoutT
// WT[n][k] = W[k][n], row-major [352][128] bf16.
// ---------------------------------------------------------------------------
__global__ void wtrans_kernel(const float* __restrict__ Wv, const float* __restrict__ Woff,
                              const float* __restrict__ Wattn, const float* __restrict__ Wout,
                              bf16_t* __restrict__ WT)
{
    const int i = blockIdx.x * 256 + threadIdx.x;   // grid covers 352*128 exactly
    const int n = i >> 7, k = i & 127;
    float v;
    if (n < 128)      v = Wv[k*128 + n];
    else if (n < 192) v = Woff[k*64 + (n-128)];
    else if (n < 224) v = Wattn[k*32 + (n-192)];
    else              v = Wout[k*128 + (n-224)];
    WT[i] = (bf16_t)v;
}

// ---------------------------------------------------------------------------
// Kernel 1: fused projections  P = query @ [Wv | Woff | Wattn] + bias
// 256 rows/block (grid 512 = exactly 2 blocks/CU, whole grid resident in one
// pass; Bt staged once per 256 rows). Operand-swapped MFMA; A = W^T tile in
// LDS (R3: de-staging thrashes L2 - keep). Two independent row-groups per
// wave for 2x MFMA/load ILP.
// Outputs: value HEAD-MAJOR [b][h][q][16]; off HEAD-MAJOR [b][h][q][8];
//          attn HEAD-MAJOR [b][h][q][4].
// ---------------------------------------------------------------------------
__global__ __launch_bounds__(512, 4)
void proj_kernel(const float* __restrict__ query, const bf16_t* __restrict__ WT,
                 const float* __restrict__ bv, const float* __restrict__ boff,
                 const float* __restrict__ battn,
                 bf16_t* __restrict__ value, bf16_t* __restrict__ offb,
                 bf16_t* __restrict__ attnb)
{
    __shared__ bf16_t Bt[NPROJ][136];   // Bt[n][k] = W[k][n], padded
    __shared__ float  bias[NPROJ];
    const int t = threadIdx.x;

    // vectorized stage: 224 rows x 16 chunks of 8 bf16
    for (int i = t; i < NPROJ*16; i += 512) {
        const int n = i >> 4, c = i & 15;
        *(bf16x8*)&Bt[n][c*8] = *(const bf16x8*)(WT + n*128 + c*8);
    }
    if (t < 128)      bias[t] = bv[t];
    else if (t < 192) bias[t] = boff[t-128];
    else if (t < 224) bias[t] = battn[t-192];
    __syncthreads();

    const int lane = t & 63;
    const int wave = t >> 6;           // 0..7
    const int ln   = lane & 15;
    const int q4   = lane >> 4;
    const int lk   = q4 * 8;

    // two row-groups per wave: rows row0 and row0+128
    const int row0 = blockIdx.x * 256 + wave * 16 + ln;

    bf16x8 qf[2][4];
    #pragma unroll
    for (int g = 0; g < 2; ++g) {
        const float* ap = query + (row0 + g*128) * CDIM + lk;
        #pragma unroll
        for (int kc = 0; kc < 4; ++kc)
            qf[g][kc] = cvt_bf16x8(ap + kc*32);
    }

    #pragma unroll 1
    for (int cb = 0; cb < 14; ++cb) {
        const int n0 = cb * 16;
        bf16x8 wf[4];
        const bf16_t* bp = &Bt[n0 + ln][lk];   // A-operand: channel n0+ln
        #pragma unroll
        for (int kc = 0; kc < 4; ++kc)
            wf[kc] = *(const bf16x8*)(bp + kc*32);

        f32x4 acc0 = {0.f, 0.f, 0.f, 0.f};
        f32x4 acc1 = {0.f, 0.f, 0.f, 0.f};
        #pragma unroll
        for (int kc = 0; kc < 4; ++kc) {
            acc0 = __builtin_amdgcn_mfma_f32_16x16x32_bf16(wf[kc], qf[0][kc], acc0, 0, 0, 0);
            acc1 = __builtin_amdgcn_mfma_f32_16x16x32_bf16(wf[kc], qf[1][kc], acc1, 0, 0, 0);
        }

        const int c0 = n0 + q4*4;              // first of 4 consecutive channels
        const f32x4 bi = *(const f32x4*)&bias[c0];

        #pragma unroll
        for (int g = 0; g < 2; ++g) {
            const f32x4 acc = g ? acc1 : acc0;
            const int row = row0 + g*128;
            const int b   = row >> 14;
            const int q   = row & (NQ - 1);
            bf16x4 s;
            #pragma unroll
            for (int r = 0; r < 4; ++r) s[r] = (bf16_t)(acc[r] + bi[r]);

            if (cb < 8) {
                const int h = c0 >> 4;          // cb == head
                *(bf16x4*)(value + (((size_t)(b*8 + h) << 14) + q)*16 + (c0 & 15)) = s;
            } else if (cb < 12) {
                const int h    = (c0 - 128) >> 3;
                const int part = (c0 - 128) & 7;        // 0 or 4
                *(bf16x4*)(offb + (((size_t)(b*8 + h) << 14) + q)*8 + part) = s;
            } else {
                const int h = (c0 - 192) >> 2;          // full logit quad
                *(bf16x4*)(attnb + (((size_t)(b*8 + h) << 14) + q)*4) = s;
            }
        }
    }
}

// ---------------------------------------------------------------------------
// Kernel 2 (fused sample + out-proj):
// Block swizzle: swz = (bid&7)*256 + bid>>3 -> XCD k owns batch k exclusively;
//   per-XCD gather working set = 8 heads x 512 KB = 4 MB = one XCD L2.
// Phase 1: 64 query rows/block; 2 lanes per (row,h) unit (8 channels each;
//          a[8] accumulators - R6/R7 proved a[16] spills at the 64-VGPR
//          allocation: WRITE_SIZE 78->731/394 MB). 16B dwordx4 tap loads from
//          head-major value; off/attn reads coalesced (head-major). u-loop
//          unrolled (2x gather ILP, measured 64.7->61 us R5).
// Phase 2: operand-swapped MFMA vs Wout^T staged in LDS (R3: de-staging
//          thrashes L2); epilogue +bout+2*query, packed float4 stores.
// ---------------------------------------------------------------------------
__global__ __launch_bounds__(512, 4)
void sample_out_kernel(const bf16_t* __restrict__ value, const bf16_t* __restrict__ offb,
                       const bf16_t* __restrict__ attnb, const bf16_t* __restrict__ WTo,
                       const float* __restrict__ bout, const float* __restrict__ query,
                       float* __restrict__ out)
{
    __shared__ bf16_t Wt[128][136];     // Wout^T
    __shared__ float  bias[128];
    __shared__ bf16_t Srow[64][136];    // sampled rows tile (pad 8)
    const int t = threadIdx.x;

    for (int i = t; i < 128*16; i += 512) {
        const int n = i >> 4, c = i & 15;
        *(bf16x8*)&Wt[n][c*8] = *(const bf16x8*)(WTo + n*128 + c*8);
    }
    if (t < 128) bias[t] = bout[t];

    // XCD-aware swizzle: grid 2048 = 8 batches x 256 blocks; bid%8 -> XCD,
    // so give XCD k the contiguous chunk [k*256, (k+1)*256) = batch k.
    const int swz      = ((blockIdx.x & 7) << 8) + (blockIdx.x >> 3);
    const int row_base = swz * 64;

    const int j   = t & 1;             // channel half (8 ch) within unit
    const int uq2 = t >> 1;            // 0..255

    #pragma unroll
    for (int u = 0; u < 2; ++u) {
        const int unit = u*256 + uq2;  // 0..511 = 8 heads x 64 rows (row-fastest)
        const int h    = unit >> 6;    // one head per wave
        const int lr   = unit & 63;    // 32 consecutive rows per wave
        const int bq   = row_base + lr;
        const int q    = bq & (NQ - 1);
        const int b    = bq >> 14;
        const size_t plane = (size_t)(b*8 + h) << 14;   // (b,h) pixel plane

        // softmax over 4 points (logits bf16; |l| < ~2, no max-sub needed)
        union { bf16x4 v; u32 d[2]; } at;
        at.v = *(const bf16x4*)(attnb + (plane + q)*4);
        float e0 = __expf(bflo(at.d[0])), e1 = __expf(bfhi(at.d[0]));
        float e2 = __expf(bflo(at.d[1])), e3 = __expf(bfhi(at.d[1]));
        float rs = 1.0f / (e0 + e1 + e2 + e3);
        const float aw[4] = {e0*rs, e1*rs, e2*rs, e3*rs};

        union { bf16x8 v; u32 d[4]; } of;
        of.v = *(const bf16x8*)(offb + (plane + q)*8);

        const float bx = (float)(q & 127) * (128.0f/127.0f) - 0.5f;
        const float by = (float)(q >> 7)  * (128.0f/127.0f) - 0.5f;

        // head-major value plane for (b,h); this lane covers channels j*8..j*8+7
        const bf16_t* vbase = value + plane*16 + j*8;

        float a[8] = {0.f,0.f,0.f,0.f,0.f,0.f,0.f,0.f};
        #pragma unroll
        for (int p = 0; p < 4; ++p) {
            float x = bx + bflo(of.d[p]);
            float y = by + bfhi(of.d[p]);
            float xf = floorf(x), yf = floorf(y);
            int   x0 = (int)xf,  y0 = (int)yf;
            float wx1 = x - xf, wy1 = y - yf;
            float wxe0 = (((unsigned)x0       < 128u) ? (1.0f - wx1) : 0.f);
            float wxe1 = (((unsigned)(x0 + 1) < 128u) ? wx1          : 0.f);
            float wye0 = (((unsigned)y0       < 128u) ? (1.0f - wy1) : 0.f) * aw[p];
            float wye1 = (((unsigned)(y0 + 1) < 128u) ? wy1          : 0.f) * aw[p];
            int xc0 = min(max(x0, 0), 127),      xc1 = min(max(x0 + 1, 0), 127);
            int rb0 = min(max(y0, 0), 127) << 7, rb1 = min(max(y0 + 1, 0), 127) << 7;

            const int   idx[4] = {rb0 + xc0, rb0 + xc1, rb1 + xc0, rb1 + xc1};
            const float wt [4] = {wxe0*wye0, wxe1*wye0, wxe0*wye1, wxe1*wye1};
            #pragma unroll
            for (int tp = 0; tp < 4; ++tp) {
                const uint4 d = *(const uint4*)(vbase + ((size_t)idx[tp] << 4));
                const float w = wt[tp];
                a[0] += w * bflo(d.x); a[1] += w * bfhi(d.x);
                a[2] += w * bflo(d.y); a[3] += w * bfhi(d.y);
                a[4] += w * bflo(d.z); a[5] += w * bfhi(d.z);
                a[6] += w * bflo(d.w); a[7] += w * bfhi(d.w);
            }
        }
        bf16x8 s;
        #pragma unroll
        for (int r = 0; r < 8; ++r) s[r] = (bf16_t)a[r];
        *(bf16x8*)(&Srow[lr][h*16 + j*8]) = s;
    }
    __syncthreads();

    // Phase 2: 8 waves x 4 jobs: row-tile rt = wave>>1, col-blocks (wave&1)*4..+3
    const int lane = t & 63;
    const int wave = t >> 6;
    const int ln   = lane & 15;
    const int q4   = lane >> 4;
    const int lk   = q4 * 8;
    const int rt   = wave >> 1;
    const int cb0  = (wave & 1) * 4;

    bf16x8 sf[4];
    const bf16_t* sp = &Srow[rt*16 + ln][lk];   // B-operand: sampled row
    #pragma unroll
    for (int kc = 0; kc < 4; ++kc)
        sf[kc] = *(const bf16x8*)(sp + kc*32);

    const int grow = row_base + rt*16 + ln;     // global row this lane stores

    #pragma unroll
    for (int c = 0; c < 4; ++c) {
        const int n0 = (cb0 + c) * 16;
        bf16x8 wf[4];
        const bf16_t* bp = &Wt[n0 + ln][lk];    // A-operand: out channel n0+ln
        #pragma unroll
        for (int kc = 0; kc < 4; ++kc)
            wf[kc] = *(const bf16x8*)(bp + kc*32);

        f32x4 acc = {0.f, 0.f, 0.f, 0.f};
        #pragma unroll
        for (int kc = 0; kc < 4; ++kc)
            acc = __builtin_amdgcn_mfma_f32_16x16x32_bf16(wf[kc], sf[kc], acc, 0, 0, 0);

        const int c0 = n0 + q4*4;
        const f32x4 bi = *(const f32x4*)&bias[c0];
        const float4 qv = *(const float4*)(query + grow*CDIM + c0);
        float4 o;
        o.x = acc[0] + bi[0] + 2.0f*qv.x;
        o.y = acc[1] + bi[1] + 2.0f*qv.y;
        o.z = acc[2] + bi[2] + 2.0f*qv.z;
        o.w = acc[3] + bi[3] + 2.0f*qv.w;
        *(float4*)(out + grow*CDIM + c0) = o;
    }
}

// ---------------------------------------------------------------------------
extern "C" void kernel_launch(void* const* d_in, const int* in_sizes, int n_in,
                              void* d_out, int out_size, void* d_ws, size_t ws_size,
                              hipStream_t stream)
{
    const float* query = (const float*)d_in[0];
    const float* Wv    = (const float*)d_in[1];
    const float* bv    = (const float*)d_in[2];
    const float* Woff  = (const float*)d_in[3];
    const float* boff  = (const float*)d_in[4];
    const float* Wattn = (const float*)d_in[5];
    const float* battn = (const float*)d_in[6];
    const float* Wout  = (const float*)d_in[7];
    const float* bout  = (const float*)d_in[8];
    float* out = (float*)d_out;

    // ws: value bf16 head-major (33.5MB) | off bf16 head-major (16.8MB)
    //     | attnl bf16 head-major (8.4MB) | WT bf16 [352][128] (90KB)
    bf16_t* value = (bf16_t*)d_ws;
    bf16_t* offb  = (bf16_t*)((char*)d_ws + (size_t)M_TOTAL*CDIM*2);
    bf16_t* attnb = (bf16_t*)((char*)d_ws + (size_t)M_TOTAL*CDIM*2 + (size_t)M_TOTAL*64*2);
    bf16_t* WT    = (bf16_t*)((char*)d_ws + (size_t)M_TOTAL*CDIM*2 + (size_t)M_TOTAL*64*2
                                          + (size_t)M_TOTAL*32*2);
    bf16_t* WTo   = WT + 224*128;

    wtrans_kernel<<<(352*128)/256, 256, 0, stream>>>(Wv, Woff, Wattn, Wout, WT);
    proj_kernel<<<M_TOTAL/256, 512, 0, stream>>>(query, WT, bv, boff, battn,
                                                 value, offb, attnb);
    sample_out_kernel<<<M_TOTAL/64, 512, 0, stream>>>(value, offb, attnb,
                                                      WTo, bout, query, out);
}

// Round 9
// 171.210 us; speedup vs baseline: 2.7695x; 1.0701x over previous
//
#include <hip/hip_runtime.h>
#include <hip/hip_bf16.h>

#define BS    8
#define NQ    16384
#define CDIM  128
#define NH    8
#define NPROJ 224            // 128 value + 64 off + 32 attn logits
#define M_TOTAL (BS*NQ)      // 131072 rows

typedef __bf16 bf16_t;
typedef __bf16 bf16x8 __attribute__((ext_vector_type(8)));
typedef __bf16 bf16x4 __attribute__((ext_vector_type(4)));
typedef float  f32x4  __attribute__((ext_vector_type(4)));
typedef float  f32x2  __attribute__((ext_vector_type(2)));
typedef unsigned int u32;

__device__ __forceinline__ bf16x8 cvt_bf16x8(const float* p) {
    float4 a = *(const float4*)p;
    float4 b = *(const float4*)(p + 4);
    bf16x8 r;
    r[0] = (bf16_t)a.x; r[1] = (bf16_t)a.y; r[2] = (bf16_t)a.z; r[3] = (bf16_t)a.w;
    r[4] = (bf16_t)b.x; r[5] = (bf16_t)b.y; r[6] = (bf16_t)b.z; r[7] = (bf16_t)b.w;
    return r;
}
__device__ __forceinline__ float bflo(u32 d) { return __uint_as_float(d << 16); }
__device__ __forceinline__ float bfhi(u32 d) { return __uint_as_float(d & 0xffff0000u); }
__device__ __forceinline__ f32x2 bfpair(u32 d) {
    f32x2 r; r[0] = __uint_as_float(d << 16); r[1] = __uint_as_float(d & 0xffff0000u);
    return r;
}

// ---------------------------------------------------------------------------
// Kernel 0: one-shot weight transpose to bf16.
// WT rows: [0,128) WvT | [128,192) WoffT | [192,224) WattnT | [224,352) WoutT
// WT[n][k] = W[k][n], row-major [352][128] bf16.
// ---------------------------------------------------------------------------
__global__ void wtrans_kernel(const float* __restrict__ Wv, const float* __restrict__ Woff,
                              const float* __restrict__ Wattn, const float* __restrict__ Wout,
                              bf16_t* __restrict__ WT)
{
    const int i = blockIdx.x * 256 + threadIdx.x;   // grid covers 352*128 exactly
    const int n = i >> 7, k = i & 127;
    float v;
    if (n < 128)      v = Wv[k*128 + n];
    else if (n < 192) v = Woff[k*64 + (n-128)];
    else if (n < 224) v = Wattn[k*32 + (n-192)];
    else              v = Wout[k*128 + (n-224)];
    WT[i] = (bf16_t)v;
}

// ---------------------------------------------------------------------------
// Kernel 1: fused projections  P = query @ [Wv | Woff | Wattn] + bias
// 256 rows/block (grid 512 = exactly 2 blocks/CU). Operand-swapped MFMA;
// A = W^T tile in LDS (R3: de-staging thrashes L2 - keep). Two independent
// row-groups per wave for 2x MFMA/load ILP.
// Outputs: value HEAD-MAJOR [b][h][q][16]; off HEAD-MAJOR [b][h][q][8];
//          attn HEAD-MAJOR [b][h][q][4].
// ---------------------------------------------------------------------------
__global__ __launch_bounds__(512, 4)
void proj_kernel(const float* __restrict__ query, const bf16_t* __restrict__ WT,
                 const float* __restrict__ bv, const float* __restrict__ boff,
                 const float* __restrict__ battn,
                 bf16_t* __restrict__ value, bf16_t* __restrict__ offb,
                 bf16_t* __restrict__ attnb)
{
    __shared__ bf16_t Bt[NPROJ][136];   // Bt[n][k] = W[k][n], padded
    __shared__ float  bias[NPROJ];
    const int t = threadIdx.x;

    // vectorized stage: 224 rows x 16 chunks of 8 bf16
    for (int i = t; i < NPROJ*16; i += 512) {
        const int n = i >> 4, c = i & 15;
        *(bf16x8*)&Bt[n][c*8] = *(const bf16x8*)(WT + n*128 + c*8);
    }
    if (t < 128)      bias[t] = bv[t];
    else if (t < 192) bias[t] = boff[t-128];
    else if (t < 224) bias[t] = battn[t-192];
    __syncthreads();

    const int lane = t & 63;
    const int wave = t >> 6;           // 0..7
    const int ln   = lane & 15;
    const int q4   = lane >> 4;
    const int lk   = q4 * 8;

    // two row-groups per wave: rows row0 and row0+128
    const int row0 = blockIdx.x * 256 + wave * 16 + ln;

    bf16x8 qf[2][4];
    #pragma unroll
    for (int g = 0; g < 2; ++g) {
        const float* ap = query + (row0 + g*128) * CDIM + lk;
        #pragma unroll
        for (int kc = 0; kc < 4; ++kc)
            qf[g][kc] = cvt_bf16x8(ap + kc*32);
    }

    #pragma unroll 1
    for (int cb = 0; cb < 14; ++cb) {
        const int n0 = cb * 16;
        bf16x8 wf[4];
        const bf16_t* bp = &Bt[n0 + ln][lk];   // A-operand: channel n0+ln
        #pragma unroll
        for (int kc = 0; kc < 4; ++kc)
            wf[kc] = *(const bf16x8*)(bp + kc*32);

        f32x4 acc0 = {0.f, 0.f, 0.f, 0.f};
        f32x4 acc1 = {0.f, 0.f, 0.f, 0.f};
        #pragma unroll
        for (int kc = 0; kc < 4; ++kc) {
            acc0 = __builtin_amdgcn_mfma_f32_16x16x32_bf16(wf[kc], qf[0][kc], acc0, 0, 0, 0);
            acc1 = __builtin_amdgcn_mfma_f32_16x16x32_bf16(wf[kc], qf[1][kc], acc1, 0, 0, 0);
        }

        const int c0 = n0 + q4*4;              // first of 4 consecutive channels
        const f32x4 bi = *(const f32x4*)&bias[c0];

        #pragma unroll
        for (int g = 0; g < 2; ++g) {
            const f32x4 acc = g ? acc1 : acc0;
            const int row = row0 + g*128;
            const int b   = row >> 14;
            const int q   = row & (NQ - 1);
            bf16x4 s;
            #pragma unroll
            for (int r = 0; r < 4; ++r) s[r] = (bf16_t)(acc[r] + bi[r]);

            if (cb < 8) {
                const int h = c0 >> 4;          // cb == head
                *(bf16x4*)(value + (((size_t)(b*8 + h) << 14) + q)*16 + (c0 & 15)) = s;
            } else if (cb < 12) {
                const int h    = (c0 - 128) >> 3;
                const int part = (c0 - 128) & 7;        // 0 or 4
                *(bf16x4*)(offb + (((size_t)(b*8 + h) << 14) + q)*8 + part) = s;
            } else {
                const int h = (c0 - 192) >> 2;          // full logit quad
                *(bf16x4*)(attnb + (((size_t)(b*8 + h) << 14) + q)*4) = s;
            }
        }
    }
}

// ---------------------------------------------------------------------------
// Kernel 2 (fused sample + out-proj):
// Block swizzle: swz = (bid&7)*256 + bid>>3 -> XCD k owns batch k exclusively;
//   per-XCD gather working set = 4 MB = one XCD L2 (R8: FETCH 121->66 MB).
// Phase 1: 64 query rows/block; 2 lanes per (row,h) unit (8 channels each;
//          a[8]-class accumulators as f32x2[4] -> v_pk_fma_f32 candidate,
//          25% fewer accumulate ops, fp32 math unchanged. R6/R7: a[16]
//          spills at 64-VGPR allocation - never widen). 16B dwordx4 tap
//          loads from head-major value; u-loop unrolled (2x gather ILP, R5).
// Phase 2: operand-swapped MFMA vs Wout^T staged in LDS (R3: de-staging
//          thrashes L2); s_setprio(1) around MFMA cluster (T5: gather-phase
//          and MFMA-phase waves from different blocks coexist per CU).
// ---------------------------------------------------------------------------
__global__ __launch_bounds__(512, 4)
void sample_out_kernel(const bf16_t* __restrict__ value, const bf16_t* __restrict__ offb,
                       const bf16_t* __restrict__ attnb, const bf16_t* __restrict__ WTo,
                       const float* __restrict__ bout, const float* __restrict__ query,
                       float* __restrict__ out)
{
    __shared__ bf16_t Wt[128][136];     // Wout^T
    __shared__ float  bias[128];
    __shared__ bf16_t Srow[64][136];    // sampled rows tile (pad 8)
    const int t = threadIdx.x;

    for (int i = t; i < 128*16; i += 512) {
        const int n = i >> 4, c = i & 15;
        *(bf16x8*)&Wt[n][c*8] = *(const bf16x8*)(WTo + n*128 + c*8);
    }
    if (t < 128) bias[t] = bout[t];

    // XCD-aware swizzle: grid 2048 = 8 batches x 256 blocks; bid%8 -> XCD,
    // so give XCD k the contiguous chunk [k*256, (k+1)*256) = batch k.
    const int swz      = ((blockIdx.x & 7) << 8) + (blockIdx.x >> 3);
    const int row_base = swz * 64;

    const int j   = t & 1;             // channel half (8 ch) within unit
    const int uq2 = t >> 1;            // 0..255

    #pragma unroll
    for (int u = 0; u < 2; ++u) {
        const int unit = u*256 + uq2;  // 0..511 = 8 heads x 64 rows (row-fastest)
        const int h    = unit >> 6;    // one head per wave
        const int lr   = unit & 63;    // 32 consecutive rows per wave
        const int bq   = row_base + lr;
        const int q    = bq & (NQ - 1);
        const int b    = bq >> 14;
        const size_t plane = (size_t)(b*8 + h) << 14;   // (b,h) pixel plane

        // softmax over 4 points (logits bf16; |l| < ~2, no max-sub needed)
        union { bf16x4 v; u32 d[2]; } at;
        at.v = *(const bf16x4*)(attnb + (plane + q)*4);
        float e0 = __expf(bflo(at.d[0])), e1 = __expf(bfhi(at.d[0]));
        float e2 = __expf(bflo(at.d[1])), e3 = __expf(bfhi(at.d[1]));
        float rs = 1.0f / (e0 + e1 + e2 + e3);
        const float aw[4] = {e0*rs, e1*rs, e2*rs, e3*rs};

        union { bf16x8 v; u32 d[4]; } of;
        of.v = *(const bf16x8*)(offb + (plane + q)*8);

        const float bx = (float)(q & 127) * (128.0f/127.0f) - 0.5f;
        const float by = (float)(q >> 7)  * (128.0f/127.0f) - 0.5f;

        // head-major value plane for (b,h); this lane covers channels j*8..j*8+7
        const bf16_t* vbase = value + plane*16 + j*8;

        f32x2 a2[4];
        #pragma unroll
        for (int r = 0; r < 4; ++r) a2[r] = (f32x2){0.f, 0.f};

        #pragma unroll
        for (int p = 0; p < 4; ++p) {
            float x = bx + bflo(of.d[p]);
            float y = by + bfhi(of.d[p]);
            float xf = floorf(x), yf = floorf(y);
            int   x0 = (int)xf,  y0 = (int)yf;
            float wx1 = x - xf, wy1 = y - yf;
            float wxe0 = (((unsigned)x0       < 128u) ? (1.0f - wx1) : 0.f);
            float wxe1 = (((unsigned)(x0 + 1) < 128u) ? wx1          : 0.f);
            float wye0 = (((unsigned)y0       < 128u) ? (1.0f - wy1) : 0.f) * aw[p];
            float wye1 = (((unsigned)(y0 + 1) < 128u) ? wy1          : 0.f) * aw[p];
            int xc0 = min(max(x0, 0), 127),      xc1 = min(max(x0 + 1, 0), 127);
            int rb0 = min(max(y0, 0), 127) << 7, rb1 = min(max(y0 + 1, 0), 127) << 7;

            const int   idx[4] = {rb0 + xc0, rb0 + xc1, rb1 + xc0, rb1 + xc1};
            const float wt [4] = {wxe0*wye0, wxe1*wye0, wxe0*wye1, wxe1*wye1};
            #pragma unroll
            for (int tp = 0; tp < 4; ++tp) {
                const uint4 d = *(const uint4*)(vbase + ((size_t)idx[tp] << 4));
                const float w = wt[tp];
                a2[0] += bfpair(d.x) * w;
                a2[1] += bfpair(d.y) * w;
                a2[2] += bfpair(d.z) * w;
                a2[3] += bfpair(d.w) * w;
            }
        }
        bf16x8 s;
        #pragma unroll
        for (int r = 0; r < 4; ++r) {
            s[2*r]   = (bf16_t)a2[r][0];
            s[2*r+1] = (bf16_t)a2[r][1];
        }
        *(bf16x8*)(&Srow[lr][h*16 + j*8]) = s;
    }
    __syncthreads();

    // Phase 2: 8 waves x 4 jobs: row-tile rt = wave>>1, col-blocks (wave&1)*4..+3
    const int lane = t & 63;
    const int wave = t >> 6;
    const int ln   = lane & 15;
    const int q4   = lane >> 4;
    const int lk   = q4 * 8;
    const int rt   = wave >> 1;
    const int cb0  = (wave & 1) * 4;

    bf16x8 sf[4];
    const bf16_t* sp = &Srow[rt*16 + ln][lk];   // B-operand: sampled row
    #pragma unroll
    for (int kc = 0; kc < 4; ++kc)
        sf[kc] = *(const bf16x8*)(sp + kc*32);

    const int grow = row_base + rt*16 + ln;     // global row this lane stores

    #pragma unroll
    for (int c = 0; c < 4; ++c) {
        const int n0 = (cb0 + c) * 16;
        bf16x8 wf[4];
        const bf16_t* bp = &Wt[n0 + ln][lk];    // A-operand: out channel n0+ln
        #pragma unroll
        for (int kc = 0; kc < 4; ++kc)
            wf[kc] = *(const bf16x8*)(bp + kc*32);

        f32x4 acc = {0.f, 0.f, 0.f, 0.f};
        __builtin_amdgcn_s_setprio(1);
        #pragma unroll
        for (int kc = 0; kc < 4; ++kc)
            acc = __builtin_amdgcn_mfma_f32_16x16x32_bf16(wf[kc], sf[kc], acc, 0, 0, 0);
        __builtin_amdgcn_s_setprio(0);

        const int c0 = n0 + q4*4;
        const f32x4 bi = *(const f32x4*)&bias[c0];
        const float4 qv = *(const float4*)(query + grow*CDIM + c0);
        float4 o;
        o.x = acc[0] + bi[0] + 2.0f*qv.x;
        o.y = acc[1] + bi[1] + 2.0f*qv.y;
        o.z = acc[2] + bi[2] + 2.0f*qv.z;
        o.w = acc[3] + bi[3] + 2.0f*qv.w;
        *(float4*)(out + grow*CDIM + c0) = o;
    }
}

// ---------------------------------------------------------------------------
extern "C" void kernel_launch(void* const* d_in, const int* in_sizes, int n_in,
                              void* d_out, int out_size, void* d_ws, size_t ws_size,
                              hipStream_t stream)
{
    const float* query = (const float*)d_in[0];
    const float* Wv    = (const float*)d_in[1];
    const float* bv    = (const float*)d_in[2];
    const float* Woff  = (const float*)d_in[3];
    const float* boff  = (const float*)d_in[4];
    const float* Wattn = (const float*)d_in[5];
    const float* battn = (const float*)d_in[6];
    const float* Wout  = (const float*)d_in[7];
    const float* bout  = (const float*)d_in[8];
    float* out = (float*)d_out;

    // ws: value bf16 head-major (33.5MB) | off bf16 head-major (16.8MB)
    //     | attnl bf16 head-major (8.4MB) | WT bf16 [352][128] (90KB)
    bf16_t* value = (bf16_t*)d_ws;
    bf16_t* offb  = (bf16_t*)((char*)d_ws + (size_t)M_TOTAL*CDIM*2);
    bf16_t* attnb = (bf16_t*)((char*)d_ws + (size_t)M_TOTAL*CDIM*2 + (size_t)M_TOTAL*64*2);
    bf16_t* WT    = (bf16_t*)((char*)d_ws + (size_t)M_TOTAL*CDIM*2 + (size_t)M_TOTAL*64*2
                                          + (size_t)M_TOTAL*32*2);
    bf16_t* WTo   = WT + 224*128;

    wtrans_kernel<<<(352*128)/256, 256, 0, stream>>>(Wv, Woff, Wattn, Wout, WT);
    proj_kernel<<<M_TOTAL/256, 512, 0, stream>>>(query, WT, bv, boff, battn,
                                                 value, offb, attnb);
    sample_out_kernel<<<M_TOTAL/64, 512, 0, stream>>>(value, offb, attnb,
                                                      WTo, bout, query, out);
}